// Round 12
// baseline (75.224 us; speedup 1.0000x reference)
//
#include <hip/hip_runtime.h>

// VQC 12-qubit statevector, batch=1024, 128 threads/block (2 waves), NR=32.
// R12 = R7 (best: 74.6us bench) with the 3 ansatz layers as a REAL LOOP
// (#pragma unroll 1) instead of straight-line code.
// Theory: every variant R0-R11 was fully-unrolled ~40-65KB of text vs 32KB
// I-cache -> instruction-fetch streaming from L2 every pass. That matches all
// observations: both pipes ~30% busy, insensitive to occupancy (co-resident
// waves walk the same PC region and miss together), to barriers, to VALU
// cuts, to stagger. Rolled layer loop shrinks text to ~26KB with a ~9KB hot
// body -> I-cache resident. Inner gate loops stay unrolled (compile-time reg
// indices); only the layer level rolls.
//
// Structure (unchanged from R7):
//   Layout A: b11=w(q0), b10..b6=reg(q1..q5), b5..b0=lane(q6..q11)
//   Layout B: b11=w(q0), b10..b5=lane(q1..q6), b4..b0=reg(q7..q11)
// Per layer: Y q1..5 reg [A]; A->B exch (fuses Y_q6; wave-local lgkm drain);
// Y q7..11 reg [B]; fused Z (4-way Gray chains); B->A exch (fuses CNOT-chain
// perm + next layer's Y_q0). Layer-0 Y_q0 folded into closed-form encoding;
// layer-2 Zs dropped. LDS theta-table (46 sincos pairs, built once/block).

#define PI_F 3.14159265358979323846f
#define NR 32
#define PAD 66   // even: 528B rows -> b128 pairs stay 16B-aligned

typedef __attribute__((ext_vector_type(2))) float v2f;
typedef __attribute__((ext_vector_type(4))) float v4f;

__device__ __forceinline__ v2f mkv(float x, float y) { v2f r; r.x = x; r.y = y; return r; }
__device__ __forceinline__ v2f cmul(v2f a, v2f b) {   // complex a*b
    return a.x * b + a.y * mkv(-b.y, b.x);
}
__device__ __forceinline__ v2f cmulc(v2f a, v2f b) {  // a * conj(b)
    return a.x * mkv(b.x, -b.y) + a.y * mkv(b.y, b.x);
}

// ---- cross-lane xor primitives (readout only) ----
template<int M>
__device__ __forceinline__ float lane_xor_f(float v) {
    if constexpr (M == 1) {        // quad_perm [1,0,3,2]
        return __int_as_float(__builtin_amdgcn_update_dpp(
            0, __float_as_int(v), 0xB1, 0xF, 0xF, false));
    } else if constexpr (M == 2) { // quad_perm [2,3,0,1]
        return __int_as_float(__builtin_amdgcn_update_dpp(
            0, __float_as_int(v), 0x4E, 0xF, 0xF, false));
    } else if constexpr (M == 4) {
        return __int_as_float(__builtin_amdgcn_ds_swizzle(__float_as_int(v), 0x101F));
    } else if constexpr (M == 8) {
        return __int_as_float(__builtin_amdgcn_ds_swizzle(__float_as_int(v), 0x201F));
    } else if constexpr (M == 16) {
        return __int_as_float(__builtin_amdgcn_ds_swizzle(__float_as_int(v), 0x401F));
    } else {                       // M == 32: cross-half
        return __shfl_xor(v, 32, 64);
    }
}

template<int RB>
__device__ __forceinline__ void ypow_reg(v2f (&a)[NR], float c, float s) {
    #pragma unroll
    for (int r0 = 0; r0 < NR; ++r0) {
        if ((r0 >> RB) & 1) continue;
        const int r1 = r0 | (1 << RB);
        v2f a0 = a[r0], a1 = a[r1];
        a[r0] = c * a0 - s * a1;
        a[r1] = s * a0 + c * a1;
    }
}

// yt = &thTab[l*12]; layout A: q1..q5 -> reg bits 4..0
__device__ __forceinline__ void ypowA(v2f (&a)[NR], const v2f* __restrict__ yt) {
    { v2f t = yt[1]; ypow_reg<4>(a, t.x, t.y); }
    { v2f t = yt[2]; ypow_reg<3>(a, t.x, t.y); }
    { v2f t = yt[3]; ypow_reg<2>(a, t.x, t.y); }
    { v2f t = yt[4]; ypow_reg<1>(a, t.x, t.y); }
    { v2f t = yt[5]; ypow_reg<0>(a, t.x, t.y); }
}
// layout B: q7..q11 -> reg bits 4..0
__device__ __forceinline__ void ypowB(v2f (&a)[NR], const v2f* __restrict__ yt) {
    { v2f t = yt[7];  ypow_reg<4>(a, t.x, t.y); }
    { v2f t = yt[8];  ypow_reg<3>(a, t.x, t.y); }
    { v2f t = yt[9];  ypow_reg<2>(a, t.x, t.y); }
    { v2f t = yt[10]; ypow_reg<1>(a, t.x, t.y); }
    { v2f t = yt[11]; ypow_reg<0>(a, t.x, t.y); }
}

// A->B transpose, fusing Y on q6 (b5). Wave-local (b11 untouched).
__device__ __forceinline__ void exchange_AB(v2f (&a)[NR], v2f* buf,
                                            int w, int lane, bool preSync,
                                            float c6, float s6) {
    v2f* wb = buf + w * (NR * PAD);
    if (preSync) __syncthreads();          // prev BA's cross-wave reads done
    #pragma unroll
    for (int r = 0; r < NR; ++r)           // slot = [b10..b6 | b4..b0 | b5]
        wb[r * PAD + (lane & 31) * 2 + (lane >> 5)] = a[r];
    asm volatile("s_waitcnt lgkmcnt(0)" ::: "memory");   // wave-local drain
    const int g = lane >> 1;               // b10..b6 of output
    const float k0 = (lane & 1) ? s6 : c6;
    const float k1 = (lane & 1) ? c6 : -s6;
    #pragma unroll
    for (int r = 0; r < NR; ++r) {
        v4f p = *(const v4f*)(&wb[g * PAD + r * 2]);   // (b5=0, b5=1) pair
        a[r] = k0 * p.xy + k1 * p.zw;
    }
}

// B->A transpose, fusing the CNOT-chain permutation (new[y] = old[y ^ (y>>1)])
// and the NEXT layer's Y_q0 (mixes b11; pairs stored adjacent).
__device__ __forceinline__ void exchange_BA(v2f (&a)[NR], v2f* buf,
                                            int w, int lane, float c0, float s0) {
    __syncthreads();                       // all waves' AB-region reads done
    const int p6w = lane ^ (w << 5);       // (x10^x11)<<5 | x9..x5 for this writer
    #pragma unroll
    for (int r = 0; r < NR; ++r)           // slot = p6*PAD + (x4..x0)*2 + x11
        buf[p6w * PAD + r * 2 + w] = a[r];
    __syncthreads();
    const float k0 = w ? s0 : c0;
    const float k1 = w ? c0 : -s0;
    #pragma unroll
    for (int rp = 0; rp < NR; ++rp) {
        const int ylow = (rp << 6) | lane;         // b10..b0 of output index
        const int t = ylow ^ (ylow >> 1);          // Gray inverse (11 bits)
        const int base = (t >> 5) * PAD + (t & 31) * 2;
        v4f p = *(const v4f*)(&buf[base]);         // (b11=0, b11=1) pair
        a[rp] = k0 * p.xy + k1 * p.zw;
    }
}

// Fused Z for all 12 qubits, layout B. Gray-code running complex product,
// split into 4 parallel sub-chains (k = 8m..8m+7) -> dependent depth ~10.
__device__ __forceinline__ void fused_z_B(v2f (&a)[NR], int w, int lane,
                                          const float* __restrict__ th,
                                          const v2f* __restrict__ zt) {
    float alpha = w ? th[1] : 0.0f;
    #pragma unroll
    for (int k = 0; k < 6; ++k)                 // lane bit k <-> q(6-k)
        alpha += ((lane >> k) & 1) ? th[2*(6-k)+1] : 0.0f;
    float zs, zc; __sincosf(PI_F * alpha, &zs, &zc);
    v2f zq[5];
    #pragma unroll
    for (int j = 0; j < 5; ++j) zq[j] = zt[j];  // reg bit j <-> q(11-j)
    const v2f base = mkv(zc, zs);
    v2f curs[4];
    curs[0] = base;
    curs[1] = cmul(base, cmul(zq[2], zq[3]));   // g(8)  = 12
    curs[2] = cmul(base, cmul(zq[3], zq[4]));   // g(16) = 24
    curs[3] = cmul(base, cmul(zq[2], zq[4]));   // g(24) = 20
    a[0]  = cmul(a[0],  curs[0]);
    a[12] = cmul(a[12], curs[1]);
    a[24] = cmul(a[24], curs[2]);
    a[20] = cmul(a[20], curs[3]);
    #pragma unroll
    for (int i = 1; i < 8; ++i) {
        #pragma unroll
        for (int m = 0; m < 4; ++m) {
            const int k = 8 * m + i;
            const int bit = __builtin_ctz(i);
            const int g = k ^ (k >> 1);
            curs[m] = ((g >> bit) & 1) ? cmul(curs[m], zq[bit])
                                       : cmulc(curs[m], zq[bit]);
            a[g] = cmul(a[g], curs[m]);
        }
    }
}

__global__ __launch_bounds__(128) void vqc_kernel(
    const float* __restrict__ inputs,   // [1024,12]
    const float* __restrict__ thetas,   // [72] = [3][12][2]
    float* __restrict__ out)            // [1024,12]
{
    __shared__ __align__(16) v2f buf[64 * PAD];   // 33,792 B exchange buffer
    __shared__ v2f thTab[46];                     // 36 Y pairs + 10 Z pairs
    __shared__ float redBuf[24];

    const int b = blockIdx.x;
    const int tid = threadIdx.x;
    const int w = tid >> 6;
    const int lane = tid & 63;
    const float* x = inputs + b * 12;

    // ---- theta table: thread-invariant sincos computed once per block.
    if (tid < 36) {
        const int l = tid / 12, q = tid % 12;
        float s, c; __sincosf(0.5f * PI_F * thetas[l * 24 + 2 * q], &s, &c);
        thTab[tid] = mkv(c, s);
    } else if (tid < 46) {
        const int j = tid - 36, l = j / 5, jj = j % 5;
        float s, c; __sincosf(PI_F * thetas[l * 24 + 2 * (11 - jj) + 1], &s, &c);
        thTab[tid] = mkv(c, s);
    }

    // ---- x-dependent encoding pieces (overlap with table fill, pre-barrier)
    float phb = 0.0f;
    #pragma unroll
    for (int k = 0; k < 6; ++k)                 // layout-A lane bit k <-> q(11-k)
        phb += ((lane >> k) & 1) ? x[11 - k] : 0.0f;
    float cbs, cbc; __sincosf(PI_F * phb, &cbs, &cbc);
    v2f cisb = mkv(cbc, cbs);
    float es, ec; __sincosf(PI_F * x[0], &es, &ec);
    v2f zr[5];
    #pragma unroll
    for (int j = 0; j < 5; ++j) {               // layout-A reg bit j <-> q(5-j)
        float ss, cc; __sincosf(PI_F * x[5 - j], &ss, &cc);
        zr[j] = mkv(cc, ss);
    }

    __syncthreads();                            // table ready

    // ---- Encoding (closed form) with layer-0 Y_q0 folded in; 4-way chains.
    v2f a[NR];
    {
        v2f t0 = thTab[0];                      // (c0, s0) of 0.5*pi*theta0
        v2f Fw = w ? mkv(t0.y + t0.x * ec,  t0.x * es)
                   : mkv(t0.x - t0.y * ec, -t0.y * es);
        const v2f g0 = cmul(Fw, cisb) * 0.015625f;
        v2f curs[4];
        curs[0] = g0;
        curs[1] = cmul(g0, cmul(zr[2], zr[3]));   // g(8)  = 12
        curs[2] = cmul(g0, cmul(zr[3], zr[4]));   // g(16) = 24
        curs[3] = cmul(g0, cmul(zr[2], zr[4]));   // g(24) = 20
        a[0] = curs[0]; a[12] = curs[1]; a[24] = curs[2]; a[20] = curs[3];
        #pragma unroll
        for (int i = 1; i < 8; ++i) {
            #pragma unroll
            for (int m = 0; m < 4; ++m) {
                const int k = 8 * m + i;
                const int bit = __builtin_ctz(i);
                const int g = k ^ (k >> 1);
                curs[m] = ((g >> bit) & 1) ? cmul(curs[m], zr[bit])
                                           : cmulc(curs[m], zr[bit]);
                a[g] = curs[m];
            }
        }
    }

    // ---- 3 ansatz layers as a REAL loop (I-cache-resident body).
    #pragma unroll 1
    for (int l = 0; l < 3; ++l) {
        const v2f* yt = &thTab[l * 12];
        ypowA(a, yt);
        { v2f t = yt[6]; exchange_AB(a, buf, w, lane, l != 0, t.x, t.y); }
        ypowB(a, yt);
        if (l < 2) {
            fused_z_B(a, w, lane, thetas + 24 * l, &thTab[36 + l * 5]);
            v2f t = thTab[(l + 1) * 12];          // next layer's Y_q0
            exchange_BA(a, buf, w, lane, t.x, t.y);
        }
    }

    // ---- Readout in layout B: b11=w(q0), lane bit k<->q(6-k), reg bit j<->q(11-j)
    float totalP = 0.0f;
    float D[5] = {0, 0, 0, 0, 0};
    #pragma unroll
    for (int r = 0; r < NR; ++r) {
        const float p = a[r].x * a[r].x + a[r].y * a[r].y;
        totalP += p;
        #pragma unroll
        for (int j = 0; j < 5; ++j)
            D[j] += ((r >> j) & 1) ? -p : p;
    }
    // q0: plain fold of totalP, sign by wave bit
    {
        float T = totalP;
        T += lane_xor_f<32>(T);
        T += lane_xor_f<16>(T);
        T += lane_xor_f<8>(T);
        T += lane_xor_f<4>(T);
        T += lane_xor_f<2>(T);
        T += lane_xor_f<1>(T);
        if (lane == 0) redBuf[w * 12 + 0] = w ? -T : T;
    }
    #pragma unroll 1
    for (int q = 1; q < 12; ++q) {
        float v;
        if (q <= 6)  v = ((lane >> (6 - q)) & 1) ? -totalP : totalP;
        else         v = D[11 - q];
        v += lane_xor_f<32>(v);
        v += lane_xor_f<16>(v);
        v += lane_xor_f<8>(v);
        v += lane_xor_f<4>(v);
        v += lane_xor_f<2>(v);
        v += lane_xor_f<1>(v);
        if (lane == 0) redBuf[w * 12 + q] = v;
    }
    __syncthreads();
    if (tid < 12) out[b * 12 + tid] = redBuf[tid] + redBuf[12 + tid];
}

extern "C" void kernel_launch(void* const* d_in, const int* in_sizes, int n_in,
                              void* d_out, int out_size, void* d_ws, size_t ws_size,
                              hipStream_t stream) {
    const float* inputs = (const float*)d_in[0];   // [1024,12] f32
    const float* thetas = (const float*)d_in[1];   // [72] f32
    float* out = (float*)d_out;                    // [1024,12] f32
    vqc_kernel<<<dim3(1024), dim3(128), 0, stream>>>(inputs, thetas, out);
}